// Round 6
// baseline (714.621 us; speedup 1.0000x reference)
//
#include <hip/hip_runtime.h>

typedef unsigned short ushort_t;  // raw bf16 bits
typedef __attribute__((ext_vector_type(4))) float f32x4;
typedef __attribute__((ext_vector_type(8))) short s16x8;
typedef __attribute__((ext_vector_type(4))) short s16x4;

#define MFMA16(a, b, c) __builtin_amdgcn_mfma_f32_16x16x32_bf16((a), (b), (c), 0, 0, 0)

__device__ __forceinline__ float us2f(unsigned short u) {
  union { unsigned int i; float f; } v; v.i = ((unsigned int)u) << 16; return v.f;
}
__device__ __forceinline__ unsigned short f2us(float f) {
  union { float f; unsigned int i; } v; v.f = f;
  unsigned int x = v.i;
  return (unsigned short)((x + 0x7FFFu + ((x >> 16) & 1u)) >> 16);
}
// load 8 consecutive f32, round to 8 bf16
__device__ __forceinline__ s16x8 ld8f(const float* p) {
  f32x4 a = *reinterpret_cast<const f32x4*>(p);
  f32x4 b = *reinterpret_cast<const f32x4*>(p + 4);
  s16x8 r;
  r[0] = (short)f2us(a[0]); r[1] = (short)f2us(a[1]);
  r[2] = (short)f2us(a[2]); r[3] = (short)f2us(a[3]);
  r[4] = (short)f2us(b[0]); r[5] = (short)f2us(b[1]);
  r[6] = (short)f2us(b[2]); r[7] = (short)f2us(b[3]);
  return r;
}
__device__ __forceinline__ float sigm(float x) { return 1.0f / (1.0f + __expf(-x)); }
__device__ __forceinline__ float tanh_f(float x) {
  float e = __expf(-2.0f * fabsf(x));
  float t = (1.0f - e) / (1.0f + e);
  return x < 0.0f ? -t : t;
}

// ---------------------------------------------------------------------------
// f32 -> bf16 conversion of whh_q | whh_p into ws (196608 elems each)
// ---------------------------------------------------------------------------
__global__ __launch_bounds__(256) void conv_k(
    const float* __restrict__ s0, const float* __restrict__ s1,
    ushort_t* __restrict__ d) {
  int i = blockIdx.x * 256 + threadIdx.x;
  if (i >= 98304) return;
  long e = (long)i * 4;
  const float* s; long off;
  if (e < 196608) { s = s0; off = e; }
  else { s = s1; off = e - 196608; }
  f32x4 v = *reinterpret_cast<const f32x4*>(s + off);
  s16x4 r;
  r[0] = (short)f2us(v[0]); r[1] = (short)f2us(v[1]);
  r[2] = (short)f2us(v[2]); r[3] = (short)f2us(v[3]);
  *reinterpret_cast<s16x4*>(d + e) = r;
}

// ---------------------------------------------------------------------------
// Generic GEMM: out[M,N] = epi(A[M,K] @ W[N,K]^T + bias)
// QKV: N=768 epilogue -> col<256: q rows (e<8) *0.125 -> qout (global rows via
// row0); col>=256: kv[row*512 + col-256]. GIT: gi permuted layout for GRU.
// ---------------------------------------------------------------------------
template <int BN, int EPI, int ROWSEL, int RELU, int AF32, int OF32, int GIT,
          int QKV, int HB>
__global__ __launch_bounds__(256) void gemm_k(
    const void* __restrict__ A_, const float* __restrict__ W,
    const float* __restrict__ bias, const int* __restrict__ em,
    void* __restrict__ out_, ushort_t* __restrict__ qout, long row0,
    int M, int N, int K) {
  constexpr int NF = (BN == 128) ? 4 : 2;
  const float* Af = (const float*)A_;
  const ushort_t* Ab = (const ushort_t*)A_;
  float* outf = (float*)out_;
  ushort_t* outb = (ushort_t*)out_;
  __shared__ ushort_t As[128 * 40];
  __shared__ ushort_t Ws[BN * 40];
  const int tid = threadIdx.x;
  const int lane = tid & 63;
  const int wid = tid >> 6;
  const int wm = wid & 1, wn = wid >> 1;
  const int m0 = blockIdx.x * 128;
  const int n0 = blockIdx.y * BN;
  const int fr = lane & 15;
  const int kb = (lane >> 4) * 8;

  f32x4 acc[4][NF];
#pragma unroll
  for (int i = 0; i < 4; i++)
#pragma unroll
    for (int j = 0; j < NF; j++) acc[i][j] = (f32x4){0.f, 0.f, 0.f, 0.f};

  for (int k0 = 0; k0 < K; k0 += 32) {
    __syncthreads();
    for (int c = tid; c < 512; c += 256) {
      int row = c >> 2, kc = (c & 3) * 8;
      int gr = m0 + row;
      long ar = ROWSEL ? ((long)(gr >> 3) * 64 + (gr & 7)) : (long)gr;
      s16x8 vv;
      if (AF32) vv = ld8f(&Af[ar * (long)K + k0 + kc]);
      else vv = *reinterpret_cast<const s16x8*>(&Ab[ar * (long)K + k0 + kc]);
      *reinterpret_cast<s16x8*>(&As[row * 40 + kc]) = vv;
    }
    for (int c = tid; c < BN * 4; c += 256) {
      int row = c >> 2, kc = (c & 3) * 8;
      *reinterpret_cast<s16x8*>(&Ws[row * 40 + kc]) =
          ld8f(&W[(long)(n0 + row) * K + k0 + kc]);
    }
    __syncthreads();
    s16x8 af[4], wf[NF];
#pragma unroll
    for (int mi = 0; mi < 4; mi++)
      af[mi] = *reinterpret_cast<const s16x8*>(&As[(wm * 64 + mi * 16 + fr) * 40 + kb]);
#pragma unroll
    for (int ni = 0; ni < NF; ni++)
      wf[ni] = *reinterpret_cast<const s16x8*>(&Ws[(wn * (BN / 2) + ni * 16 + fr) * 40 + kb]);
#pragma unroll
    for (int mi = 0; mi < 4; mi++)
#pragma unroll
      for (int ni = 0; ni < NF; ni++) acc[mi][ni] = MFMA16(af[mi], wf[ni], acc[mi][ni]);
  }

  const int rb = (lane >> 4) * 4;
#pragma unroll
  for (int ni = 0; ni < NF; ni++) {
    int col = n0 + wn * (BN / 2) + ni * 16 + fr;
    float bv = HB ? bias[col] : 0.0f;
#pragma unroll
    for (int mi = 0; mi < 4; mi++) {
#pragma unroll
      for (int rr = 0; rr < 4; rr++) {
        int row = m0 + wm * 64 + mi * 16 + rb + rr;
        float v = acc[mi][ni][rr] + bv;
        if (RELU) v = fmaxf(v, 0.0f);
        if (EPI == 2 || EPI == 3) {
          if (em[(long)(row >> 3) * 64 + (row & 7)] != 0) v = (EPI == 2) ? 0.0f : -1.0e10f;
        }
        if (QKV) {
          long grow = row0 + row;
          int e = (int)(grow & 63);
          if (col < 256) {
            if (e < 8) qout[((grow >> 6) * 8 + e) * 256 + col] = f2us(v * 0.125f);
          } else {
            outb[(long)row * 512 + (col - 256)] = f2us(v);
          }
        } else if (GIT) {
          int t = (row >> 3) & 63, bs = row >> 9, na = row & 7;
          int chain = bs * 8 + na;
          int g = col >> 8, cw = col & 255;
          outb[(((long)t * 3 + g) * 16 + (chain >> 4)) * 4096 + cw * 16 + (chain & 15)] =
              f2us(v);
        } else if (OF32) {
          outf[(long)row * N + col] = v;
        } else {
          outb[(long)row * N + col] = f2us(v);
        }
      }
    }
  }
}

// ---------------------------------------------------------------------------
// Attention core: one block per batch. q (pre-scaled) from qbuf, k/v from kv
// buffer (chunk-local rows). MFMA QK^T, 16-lane-parallel softmax, parallel PV.
// 512 threads = 8 waves: wave -> (head, n-pair) for QK^T.
// ---------------------------------------------------------------------------
__global__ __launch_bounds__(512) void attn2_k(
    const ushort_t* __restrict__ kv, const ushort_t* __restrict__ qbuf,
    const int* __restrict__ obs, ushort_t* __restrict__ attn_out, int b0) {
  __shared__ ushort_t qs[16 * 264];
  __shared__ ushort_t ks[64 * 264];
  __shared__ ushort_t vs[64 * 264];
  __shared__ float lg[32 * 66];
  __shared__ int oms[512];

  const int b_loc = blockIdx.x;
  const long b = b0 + b_loc;
  const int tid = threadIdx.x;
  const int lane = tid & 63;
  const int w = tid >> 6;
  const int fr = lane & 15, kb = (lane >> 4) * 8, rb = (lane >> 4) * 4;

  oms[tid] = obs[b * 4096 + tid];  // rows a=0..7 of obs_mask[b]
  // q rows 0..7 load, rows 8..15 zero
  {
    int row = tid >> 5, cc = (tid & 31) * 8;
    if (tid < 256) {
      *reinterpret_cast<s16x8*>(&qs[row * 264 + cc]) =
          *reinterpret_cast<const s16x8*>(&qbuf[(b * 8 + row) * 256 + cc]);
    } else {
      *reinterpret_cast<s16x8*>(&qs[row * 264 + cc]) = (s16x8){0,0,0,0,0,0,0,0};
    }
  }
  // k, v staging (coalesced 16B, 16 rows per iteration)
  for (int i = 0; i < 4; i++) {
    int e = i * 16 + (tid >> 5);
    int cc = (tid & 31) * 8;
    const ushort_t* src = &kv[((long)(b_loc * 64 + e)) * 512];
    *reinterpret_cast<s16x8*>(&ks[e * 264 + cc]) =
        *reinterpret_cast<const s16x8*>(&src[cc]);
    *reinterpret_cast<s16x8*>(&vs[e * 264 + cc]) =
        *reinterpret_cast<const s16x8*>(&src[256 + cc]);
  }
  __syncthreads();

  // QK^T via MFMA: wave w -> head h = w>>1, n-pair np = w&1 (e-tiles np*2, np*2+1)
  {
    const int h = w >> 1, np = w & 1;
    f32x4 lacc[2];
    lacc[0] = (f32x4){0.f, 0.f, 0.f, 0.f};
    lacc[1] = (f32x4){0.f, 0.f, 0.f, 0.f};
#pragma unroll
    for (int k0 = 0; k0 < 64; k0 += 32) {
      s16x8 af = *reinterpret_cast<const s16x8*>(&qs[fr * 264 + h * 64 + k0 + kb]);
#pragma unroll
      for (int j = 0; j < 2; j++) {
        int e0 = (np * 2 + j) * 16;
        s16x8 bf = *reinterpret_cast<const s16x8*>(&ks[(e0 + fr) * 264 + h * 64 + k0 + kb]);
        lacc[j] = MFMA16(af, bf, lacc[j]);
      }
    }
#pragma unroll
    for (int j = 0; j < 2; j++) {
      int e = (np * 2 + j) * 16 + fr;
#pragma unroll
      for (int rr = 0; rr < 4; rr++) {
        int a = rb + rr;
        if (a < 8)
          lg[(a * 4 + h) * 66 + e] = (oms[a * 64 + e] != 0) ? -1.0e30f : lacc[j][rr];
      }
    }
  }
  __syncthreads();

  // softmax: 32 rows x 16 lanes; each lane holds 4 e-values
  {
    int ri = tid >> 4, sub = tid & 15;
    float v4[4];
#pragma unroll
    for (int j = 0; j < 4; j++) v4[j] = lg[ri * 66 + sub * 4 + j];
    float m = fmaxf(fmaxf(v4[0], v4[1]), fmaxf(v4[2], v4[3]));
#pragma unroll
    for (int d = 1; d < 16; d <<= 1) m = fmaxf(m, __shfl_xor(m, d));
    bool dead = (m < -5.0e29f);
    float s = 0.0f;
#pragma unroll
    for (int j = 0; j < 4; j++) { v4[j] = __expf(v4[j] - m); s += v4[j]; }
#pragma unroll
    for (int d = 1; d < 16; d <<= 1) s += __shfl_xor(s, d);
    float inv = dead ? 0.0f : (1.0f / s);
#pragma unroll
    for (int j = 0; j < 4; j++) lg[ri * 66 + sub * 4 + j] = v4[j] * inv;
  }
  __syncthreads();

  // PV: thread -> (a, 4 d-cols); out[a][d] = sum_e w[a][h(d)][e] * v[e][d]
  {
    int a = tid >> 6, d0 = (tid & 63) * 4, h = d0 >> 6;
    const float* wrow = &lg[(a * 4 + h) * 66];
    float facc[4] = {0.f, 0.f, 0.f, 0.f};
    for (int e = 0; e < 64; e++) {
      float wv = wrow[e];
      s16x4 vv = *reinterpret_cast<const s16x4*>(&vs[e * 264 + d0]);
#pragma unroll
      for (int j = 0; j < 4; j++) facc[j] += wv * us2f((unsigned short)vv[j]);
    }
    s16x4 r;
#pragma unroll
    for (int j = 0; j < 4; j++) r[j] = (short)f2us(facc[j]);
    *reinterpret_cast<s16x4*>(&attn_out[(b * 8 + a) * 256 + d0]) = r;
  }
}

// ---------------------------------------------------------------------------
// GRU scan v3 (unchanged, passing): chain-split, zero inter-block comms.
// ---------------------------------------------------------------------------
__global__ __launch_bounds__(1024) void gru3_k(
    const ushort_t* __restrict__ giT_q, const ushort_t* __restrict__ giT_p,
    const ushort_t* __restrict__ whhb_q, const ushort_t* __restrict__ whhb_p,
    const float* __restrict__ bhh_q, const float* __restrict__ bhh_p,
    const float* __restrict__ h0_q, const float* __restrict__ h0_p,
    float* __restrict__ hs_q, float* __restrict__ hs_p) {
  __shared__ ushort_t nw[256 * 256];  // n-gate weights, swizzled, 128KB
  __shared__ ushort_t hls[16 * 260];  // h staging
  const int bid = blockIdx.x;
  const int mdl = bid >> 4, cg = bid & 15;
  const ushort_t* giT = mdl ? giT_p : giT_q;
  const ushort_t* whh = mdl ? whhb_p : whhb_q;
  const float* bhh = mdl ? bhh_p : bhh_q;
  const float* h0 = mdl ? h0_p : h0_q;
  float* hs = mdl ? hs_p : hs_q;

  const int tid = threadIdx.x;
  const int lane = tid & 63, w = tid >> 6;
  const int fr = lane & 15, kb = (lane >> 4) * 8, rb = (lane >> 4) * 4;
  const int col = w * 16 + fr;

  s16x8 wrz[2][8];
#pragma unroll
  for (int g = 0; g < 2; g++)
#pragma unroll
    for (int ks = 0; ks < 8; ks++)
      wrz[g][ks] = *reinterpret_cast<const s16x8*>(
          &whh[(g * 256 + col) * 256 + ks * 32 + kb]);

  char* nwb = (char*)nw;
  for (int c = tid; c < 8192; c += 1024) {
    int row = c >> 5, kc = (c & 31) * 8;
    *reinterpret_cast<s16x8*>(nwb + row * 512 + ((kc * 2) ^ ((row & 7) << 4))) =
        *reinterpret_cast<const s16x8*>(&whh[(512 + row) * 256 + kc]);
  }

  float h[4], bh[3];
#pragma unroll
  for (int rr = 0; rr < 4; rr++) h[rr] = h0[(cg * 16 + rb + rr) * 256 + col];
#pragma unroll
  for (int g = 0; g < 3; g++) bh[g] = bhh[g * 256 + col];

  long hsb[4];
#pragma unroll
  for (int rr = 0; rr < 4; rr++) {
    int chain = cg * 16 + rb + rr;
    hsb[rr] = ((long)((chain >> 3) * 64) * 8 + (chain & 7)) * 256 + col;
  }

  for (int t = 0; t < 64; t++) {
    s16x4 gv[3];
#pragma unroll
    for (int g = 0; g < 3; g++)
      gv[g] = *reinterpret_cast<const s16x4*>(
          &giT[(((long)t * 3 + g) * 16 + cg) * 4096 + col * 16 + rb]);
#pragma unroll
    for (int rr = 0; rr < 4; rr++) hls[(rb + rr) * 260 + col] = f2us(h[rr]);
    __syncthreads();
    f32x4 acc[3];
#pragma unroll
    for (int i = 0; i < 3; i++) acc[i] = (f32x4){0.f, 0.f, 0.f, 0.f};
#pragma unroll
    for (int ks = 0; ks < 8; ks++) {
      s16x8 a = *reinterpret_cast<const s16x8*>(&hls[fr * 260 + ks * 32 + kb]);
      acc[0] = MFMA16(a, wrz[0][ks], acc[0]);
      acc[1] = MFMA16(a, wrz[1][ks], acc[1]);
      s16x8 bn = *reinterpret_cast<const s16x8*>(
          nwb + col * 512 + (((ks * 32 + kb) * 2) ^ ((col & 7) << 4)));
      acc[2] = MFMA16(a, bn, acc[2]);
    }
    __syncthreads();
#pragma unroll
    for (int rr = 0; rr < 4; rr++) {
      float r_ = sigm(us2f((unsigned short)gv[0][rr]) + acc[0][rr] + bh[0]);
      float z_ = sigm(us2f((unsigned short)gv[1][rr]) + acc[1][rr] + bh[1]);
      float n_ = tanh_f(us2f((unsigned short)gv[2][rr]) + r_ * (acc[2][rr] + bh[2]));
      float hn = (1.0f - z_) * n_ + z_ * h[rr];
      h[rr] = hn;
      hs[hsb[rr] + (long)t * 2048] = hn;
    }
  }
}

// ---------------------------------------------------------------------------
extern "C" void kernel_launch(void* const* d_in, const int* in_sizes, int n_in,
                              void* d_out, int out_size, void* d_ws, size_t ws_size,
                              hipStream_t stream) {
  (void)in_sizes; (void)n_in; (void)out_size;

  const float* entities = (const float*)d_in[0];
  const int* obs = (const int*)d_in[1];
  const int* em = (const int*)d_in[2];
  const float* hidq = (const float*)d_in[3];
  const float* hidp = (const float*)d_in[4];
  const float* q_fc1_w = (const float*)d_in[5];
  const float* q_fc1_b = (const float*)d_in[6];
  const float* q_fc2_w = (const float*)d_in[7];
  const float* q_fc2_b = (const float*)d_in[8];
  const float* q_wih = (const float*)d_in[9];
  const float* q_whh = (const float*)d_in[10];
  const float* q_bih = (const float*)d_in[11];
  const float* q_bhh = (const float*)d_in[12];
  const float* q_fcq_w = (const float*)d_in[13];
  const float* q_fcq_b = (const float*)d_in[14];
  const float* q_fcpi_w = (const float*)d_in[15];
  const float* q_fcpi_b = (const float*)d_in[16];
  const float* p_fc1_w = (const float*)d_in[17];
  const float* p_fc1_b = (const float*)d_in[18];
  const float* p_fc2_w = (const float*)d_in[19];
  const float* p_fc2_b = (const float*)d_in[20];
  const float* p_wih = (const float*)d_in[21];
  const float* p_whh = (const float*)d_in[22];
  const float* p_bih = (const float*)d_in[23];
  const float* p_bhh = (const float*)d_in[24];
  const float* p_fcpi_w = (const float*)d_in[27];
  const float* p_fcpi_b = (const float*)d_in[28];
  const float* inw = (const float*)d_in[29];
  const float* outw = (const float*)d_in[30];
  const float* outb = (const float*)d_in[31];

  ushort_t* ws = (ushort_t*)d_ws;
  // chunked (safe, 68.4MB) vs unchunked (219MB) layouts
  const int big = (ws_size >= (size_t)218890240) ? 1 : 0;
  const int nc = big ? 1 : 4;
  const int CB = 2048 / nc;            // batches per chunk
  const long MR = (long)CB * 64;       // entity rows per chunk

  ushort_t* qbuf = ws;                               // [0, 4.19M)
  ushort_t* attn = ws + 4194304l;                    // [4.19M, 8.39M)
  ushort_t* x1c = ws + 8388608l;                     // chunk x1
  ushort_t* kvc = big ? (ws + 41943040l) : (ws + 16777216l);
  ushort_t* wcv = big ? (ws + 109051904l) : (ws + 33554432l);
  ushort_t* wbq = wcv;                               // whh_q bf16
  ushort_t* wbp = wcv + 196608l;                     // whh_p bf16
  // post-attn overlays
  ushort_t* x2b = ws + 8388608l;
  ushort_t* x3q = ws + 20971520l;
  ushort_t* giq = ws + 8388608l;                     // [8.39M, 20.97M)
  ushort_t* x1p = ws + 4194304l;
  ushort_t* x3p = ws;
  ushort_t* gip = ws + 20971520l;                    // [20.97M, 33.55M)

  float* out = (float*)d_out;
  float* o_q = out;
  float* o_pi = out + 1048576l;
  float* o_piA = out + 2097152l;
  float* o_hq = out + 3145728l;
  float* o_hp = out + 7340032l;

  // 0) whh -> bf16
  conv_k<<<384, 256, 0, stream>>>(q_whh, p_whh, wcv);

  // 1) q-module attention path, chunked
  for (int c = 0; c < nc; c++) {
    // x1 = relu(ent_chunk @ fc1^T + b)
    gemm_k<128, 0, 0, 1, 1, 0, 0, 0, 1><<<dim3(MR / 128, 2), 256, 0, stream>>>(
        entities + (long)c * MR * 128, q_fc1_w, q_fc1_b, em, x1c, nullptr, 0,
        (int)MR, 256, 128);
    // kvq = x1 @ in_w^T  (q scaled 1/8 -> qbuf; k,v -> kvc)
    gemm_k<128, 0, 0, 0, 0, 0, 0, 1, 0><<<dim3(MR / 128, 6), 256, 0, stream>>>(
        x1c, inw, q_fc1_b, em, kvc, qbuf, (long)c * MR, (int)MR, 768, 256);
    // attention core
    attn2_k<<<CB, 512, 0, stream>>>(kvc, qbuf, obs, attn, c * CB);
  }
  // 2) x2 = mask0(attn @ outw^T + outb)
  gemm_k<128, 2, 0, 0, 0, 0, 0, 0, 1><<<dim3(128, 2), 256, 0, stream>>>(
      attn, outw, outb, em, x2b, nullptr, 0, 16384, 256, 256);
  // 3) x3q = relu(x2 @ fc2^T + b)
  gemm_k<128, 0, 0, 1, 0, 0, 0, 0, 1><<<dim3(128, 2), 256, 0, stream>>>(
      x2b, q_fc2_w, q_fc2_b, em, x3q, nullptr, 0, 16384, 256, 256);
  // 4) gi_q = x3q @ wih^T + bih (GIT layout)
  gemm_k<128, 0, 0, 0, 0, 0, 1, 0, 1><<<dim3(128, 6), 256, 0, stream>>>(
      x3q, q_wih, q_bih, em, giq, nullptr, 0, 16384, 768, 256);
  // 5) x1p = relu(ent[:, :8] @ fc1^T + b)
  gemm_k<128, 0, 1, 1, 1, 0, 0, 0, 1><<<dim3(128, 2), 256, 0, stream>>>(
      entities, p_fc1_w, p_fc1_b, em, x1p, nullptr, 0, 16384, 256, 128);
  // 6) x3p = relu(x1p @ fc2^T + b)
  gemm_k<128, 0, 0, 1, 0, 0, 0, 0, 1><<<dim3(128, 2), 256, 0, stream>>>(
      x1p, p_fc2_w, p_fc2_b, em, x3p, nullptr, 0, 16384, 256, 256);
  // 7) gi_p (GIT layout)
  gemm_k<128, 0, 0, 0, 0, 0, 1, 0, 1><<<dim3(128, 6), 256, 0, stream>>>(
      x3p, p_wih, p_bih, em, gip, nullptr, 0, 16384, 768, 256);
  // 8) GRU scan
  gru3_k<<<32, 1024, 0, stream>>>(giq, gip, wbq, wbp, q_bhh, p_bhh, hidq, hidp,
                                  o_hq, o_hp);
  // 9) heads
  gemm_k<64, 2, 0, 0, 1, 1, 0, 0, 1><<<dim3(128, 1), 256, 0, stream>>>(
      o_hq, q_fcq_w, q_fcq_b, em, o_q, nullptr, 0, 16384, 64, 256);
  gemm_k<64, 3, 0, 0, 1, 1, 0, 0, 1><<<dim3(128, 1), 256, 0, stream>>>(
      o_hq, q_fcpi_w, q_fcpi_b, em, o_pi, nullptr, 0, 16384, 64, 256);
  gemm_k<64, 3, 0, 0, 1, 1, 0, 0, 1><<<dim3(128, 1), 256, 0, stream>>>(
      o_hp, p_fcpi_w, p_fcpi_b, em, o_piA, nullptr, 0, 16384, 64, 256);
}